// Round 3
// baseline (272.598 us; speedup 1.0000x reference)
//
#include <hip/hip_runtime.h>

// Embedding gather: out[row, :] = weight[input[row], :]
// rows = 16384, EMSIZE = 1024 fp32 (4 KB/row) -> 64 MiB out, ~63 MiB unique reads.
// Persistent grid-stride: 2048 blocks x 256 threads, each thread moves 8 float4.
// Row index broadcasts (whole aligned 256-chunk maps to one row). Non-temporal
// stores keep the streamed 64 MiB output from evicting weight rows in L2/L3.
// Note: __builtin_nontemporal_store needs a clang ext_vector, not HIP float4.

typedef float floatx4 __attribute__((ext_vector_type(4)));

constexpr int VEC_PER_ROW = 256;                 // 1024 floats / 4
constexpr int TOTAL_VEC   = 16384 * VEC_PER_ROW; // 4,194,304 float4
constexpr int BLOCKS      = 2048;
constexpr int THREADS     = 256;

__global__ __launch_bounds__(THREADS)
void EmbeddingMul_73564199845928_kernel(const int* __restrict__ idx,
                                        const floatx4* __restrict__ w,
                                        floatx4* __restrict__ out) {
    const int stride = BLOCKS * THREADS;         // 524,288
    int g = blockIdx.x * THREADS + threadIdx.x;
    #pragma unroll
    for (int it = 0; it < TOTAL_VEC / (BLOCKS * THREADS); ++it, g += stride) {
        const int row   = g >> 8;                // float4 index -> row
        const int col   = g & (VEC_PER_ROW - 1);
        const int token = idx[row];              // block-uniform broadcast
        const floatx4 v = w[token * VEC_PER_ROW + col];
        __builtin_nontemporal_store(v, &out[g]);
    }
}

extern "C" void kernel_launch(void* const* d_in, const int* in_sizes, int n_in,
                              void* d_out, int out_size, void* d_ws, size_t ws_size,
                              hipStream_t stream) {
    const int*     idx = (const int*)d_in[0];
    const floatx4* w   = (const floatx4*)d_in[1];
    floatx4*       out = (floatx4*)d_out;

    EmbeddingMul_73564199845928_kernel<<<BLOCKS, THREADS, 0, stream>>>(idx, w, out);
}

// Round 4
// 269.496 us; speedup vs baseline: 1.0115x; 1.0115x over previous
//
#include <hip/hip_runtime.h>

// Embedding gather: out[row, :] = weight[input[row], :]
// rows = 2048*8 = 16384, EMSIZE = 1024 fp32 (4 KB/row).
// One 256-thread block per row; each thread copies one float4.
// Fully coalesced read (contiguous 4 KB row) and write.
//
// R3 post-mortem: persistent grid-stride + nontemporal stores = 272.6 µs vs
// this structure's 269.7 µs. Plain stores win slightly: 64 MiB output is
// absorbed by L2/L3 and written back off the critical path, while nt forces
// HBM writes inside the kernel window. Timed 270 µs is dominated by harness
// ops (785 MiB ws poison ~125 µs @ 81% HBM peak, weight restore ~70 µs,
// out poison ~10 µs); kernel slice ~20-40 µs is at its BW floor.

constexpr int VEC_PER_ROW = 256;   // 1024 floats / 4 per row

__global__ __launch_bounds__(256)
void EmbeddingMul_73564199845928_kernel(const int* __restrict__ idx,
                                        const float4* __restrict__ w,
                                        float4* __restrict__ out) {
    const int g   = blockIdx.x * 256 + threadIdx.x;   // global float4 id
    const int row = g >> 8;                           // 256 float4 per row
    const int col = g & (VEC_PER_ROW - 1);
    const int token = idx[row];                       // block-uniform broadcast
    out[g] = w[token * VEC_PER_ROW + col];
}

extern "C" void kernel_launch(void* const* d_in, const int* in_sizes, int n_in,
                              void* d_out, int out_size, void* d_ws, size_t ws_size,
                              hipStream_t stream) {
    const int*    idx = (const int*)d_in[0];
    const float4* w   = (const float4*)d_in[1];
    float4*       out = (float4*)d_out;

    const int total_vec = out_size / 4;          // 4,194,304 float4
    const int blocks    = total_vec / 256;       // 16384 (one block per row)

    EmbeddingMul_73564199845928_kernel<<<blocks, 256, 0, stream>>>(idx, w, out);
}